// Round 5
// baseline (233.511 us; speedup 1.0000x reference)
//
#include <hip/hip_runtime.h>
#include <hip/hip_bf16.h>

// GroupContrast loss. Per-row reductions instead of the 8192x8192 logits:
//   sE_i = sum_{j != i} exp(100*acc_ij - 100)   (dense, MFMA, SYMMETRIC:
//     only upper-triangle 128x128 tiles computed; row sums -> sE[i],
//     col sums -> sE[j]; acc is bitwise-symmetric since mfma(fi,fj) and
//     mfma(fj,fi) form identical products in identical k-order)
//   sP_i = sum_pos exp(..), sA_i = sum_pos acc  (sparse per-group blocks,
//     same MFMA chain -> bitwise-identical acc, so Q = sE - sP is safe)
//   final: Z = sP/pc + (sE-sP)/nc;
//          mlpp = 100*sA/pc - 100 - log(pc) - log(Z); loss = -T*mean_valid.
// NOTE: VGPR cap pitfall — (256,4) spills afr[][] to scratch (round-3:
// 328MB FETCH, 2x slower). Keep (256,2).

#define N_ROWS 8192
#define D_PAD 320
#define NG 100
#define TEMP 0.01f
#define LOG2E100 144.2695041f      // 100 * log2(e)

typedef short short8v __attribute__((ext_vector_type(8)));
typedef float float4v __attribute__((ext_vector_type(4)));

__device__ __forceinline__ short f2bf(float f) {
  union { __hip_bfloat16 h; short s; } u;
  u.h = __float2bfloat16(f);
  return u.s;
}

// ---------- setup: W1/W2 -> bf16 Wt[320 n][320 k] (LDS-tiled transpose) + hist ----------
__global__ __launch_bounds__(256) void setup_kernel(
    const float* __restrict__ W1, const float* __restrict__ W2,
    const int* __restrict__ labels,
    __hip_bfloat16* __restrict__ w1t, __hip_bfloat16* __restrict__ w2t,
    int* __restrict__ counts)
{
  __shared__ float T[64][65];
  __shared__ int hc[NG + 1];
  int b = blockIdx.x, tid = threadIdx.x;
  if (b < 50) {                          // 25 tiles per matrix, 64x64
    int isW2 = b >= 25;
    int t5 = isW2 ? b - 25 : b;
    int k0 = (t5 / 5) * 64, n0 = (t5 % 5) * 64;
    const float* W = isW2 ? W2 : W1;
    __hip_bfloat16* dst = isW2 ? w2t : w1t;
#pragma unroll
    for (int t = 0; t < 16; ++t) {       // coalesced read along n
      int e = tid + t * 256;
      int r = e >> 6, c = e & 63;
      T[r][c] = (k0 + r < 300 && n0 + c < 300)
                  ? W[(size_t)(k0 + r) * 300 + (n0 + c)] : 0.0f;
    }
    __syncthreads();
#pragma unroll
    for (int t = 0; t < 16; ++t) {       // coalesced write along k
      int e = tid + t * 256;
      int nn = e >> 6, kk = e & 63;
      dst[(size_t)(n0 + nn) * D_PAD + (k0 + kk)] = __float2bfloat16(T[kk][nn]);
    }
  } else {                               // histogram, 32 blocks x 256 rows
    if (tid <= NG) hc[tid] = 0;
    __syncthreads();
    int row = (b - 50) * 256 + tid;
    atomicAdd(&hc[labels[row]], 1);
    __syncthreads();
    if (tid <= NG && hc[tid] > 0) atomicAdd(&counts[tid], hc[tid]);
  }
}

// ---------- fused MLP + rownorm: x -> fb (bf16, unit rows, padded to 320) ----------
// 256 blocks x 128 threads (2 waves), 32 rows/block -> full GPU coverage.
__global__ __launch_bounds__(128, 2) void mlp_fused_kernel(
    const float* __restrict__ x, const __hip_bfloat16* __restrict__ w1t,
    const __hip_bfloat16* __restrict__ w2t, const float* __restrict__ b1,
    const float* __restrict__ b2, __hip_bfloat16* __restrict__ fb)
{
  __shared__ __align__(16) short Ws[64 * D_PAD];   // 40960 B, W chunk (swizzled)
  __shared__ __align__(16) short H1[32 * D_PAD];   // 20480 B, h1 tile (swizzled)
  int tid = threadIdx.x;
  int lane = tid & 63, wave = tid >> 6;            // wave in {0,1}
  int g = lane >> 4, lc = lane & 15, sw = lc & 7;
  int i0 = blockIdx.x * 32;

  // ---- A-frags from x: rows wave*16+lc, cols kk*32+g*8..+8 (fp32 -> bf16) ----
  short8v afr[10];
  {
    const float* xp = x + (size_t)(i0 + wave * 16 + lc) * 300;
#pragma unroll
    for (int kk = 0; kk < 10; ++kk) {
      int k0 = kk * 32 + g * 8;
      short8v v;
      if (k0 + 8 <= 300) {
        float4 a = *(const float4*)(xp + k0);
        float4 c = *(const float4*)(xp + k0 + 4);
        v[0] = f2bf(a.x); v[1] = f2bf(a.y); v[2] = f2bf(a.z); v[3] = f2bf(a.w);
        v[4] = f2bf(c.x); v[5] = f2bf(c.y); v[6] = f2bf(c.z); v[7] = f2bf(c.w);
      } else if (k0 < 300) {     // k0 == 296
        float4 a = *(const float4*)(xp + k0);
        v[0] = f2bf(a.x); v[1] = f2bf(a.y); v[2] = f2bf(a.z); v[3] = f2bf(a.w);
        v[4] = 0; v[5] = 0; v[6] = 0; v[7] = 0;
      } else {
        v = short8v{0, 0, 0, 0, 0, 0, 0, 0};
      }
      afr[kk] = v;
    }
  }

  // ---- GEMM1: h1 = relu(x @ W1 + b1) -> H1 (bf16, swizzled) ----
  for (int c = 0; c < 5; ++c) {
    __syncthreads();
    {
      const int4* src = (const int4*)w1t;
      int4* dst = (int4*)Ws;
#pragma unroll
      for (int t = 0; t < 20; ++t) {
        int e = tid + t * 128;
        int r = e / 40, q = e - r * 40;
        dst[r * 40 + (q ^ (r & 7))] = src[(size_t)(c * 64 + r) * 40 + q];
      }
    }
    __syncthreads();
    for (int js = 0; js < 4; ++js) {
      float4v acc = {0.f, 0.f, 0.f, 0.f};
      const short* rowp = Ws + (js * 16 + lc) * D_PAD;
#pragma unroll
      for (int kk = 0; kk < 10; ++kk) {
        short8v bf = *(const short8v*)(rowp + (((g + 4 * kk) ^ sw) << 3));
        acc = __builtin_amdgcn_mfma_f32_16x16x32_bf16(afr[kk], bf, acc, 0, 0, 0);
      }
      int n = c * 64 + js * 16 + lc;
      float bv = (n < 300) ? b1[n] : 0.0f;
#pragma unroll
      for (int r = 0; r < 4; ++r) {
        int row = wave * 16 + g * 4 + r;
        int q = n >> 3;
        H1[row * D_PAD + ((q ^ (row & 7)) << 3) + (n & 7)] =
            f2bf(fmaxf(acc[r] + bv, 0.0f));
      }
    }
  }
  __syncthreads();   // H1 complete

  // ---- h1 A-frags from LDS ----
  short8v hfr[10];
  {
    const short* rp = H1 + (wave * 16 + lc) * D_PAD;
#pragma unroll
    for (int kk = 0; kk < 10; ++kk)
      hfr[kk] = *(const short8v*)(rp + (((g + 4 * kk) ^ sw) << 3));
  }

  // ---- GEMM2: h2 = h1 @ W2 + b2, kept in registers ----
  float4v h2a[5][4];
  for (int c = 0; c < 5; ++c) {
    __syncthreads();
    {
      const int4* src = (const int4*)w2t;
      int4* dst = (int4*)Ws;
#pragma unroll
      for (int t = 0; t < 20; ++t) {
        int e = tid + t * 128;
        int r = e / 40, q = e - r * 40;
        dst[r * 40 + (q ^ (r & 7))] = src[(size_t)(c * 64 + r) * 40 + q];
      }
    }
    __syncthreads();
#pragma unroll
    for (int js = 0; js < 4; ++js) {
      float4v acc = {0.f, 0.f, 0.f, 0.f};
      const short* rowp = Ws + (js * 16 + lc) * D_PAD;
#pragma unroll
      for (int kk = 0; kk < 10; ++kk) {
        short8v bf = *(const short8v*)(rowp + (((g + 4 * kk) ^ sw) << 3));
        acc = __builtin_amdgcn_mfma_f32_16x16x32_bf16(hfr[kk], bf, acc, 0, 0, 0);
      }
      int n = c * 64 + js * 16 + lc;
      float bv = (n < 300) ? b2[n] : 0.0f;
#pragma unroll
      for (int r = 0; r < 4; ++r) acc[r] += bv;   // pad cols: W/b pads=0 -> h2=0
      h2a[c][js] = acc;
    }
  }

  // ---- row ssq (shuffle across the 16 lc lanes) + normalize + store ----
  float ssq[4] = {0.f, 0.f, 0.f, 0.f};
#pragma unroll
  for (int c = 0; c < 5; ++c)
#pragma unroll
    for (int js = 0; js < 4; ++js)
#pragma unroll
      for (int r = 0; r < 4; ++r) ssq[r] = fmaf(h2a[c][js][r], h2a[c][js][r], ssq[r]);
  for (int m = 1; m < 16; m <<= 1)
#pragma unroll
    for (int r = 0; r < 4; ++r) ssq[r] += __shfl_xor(ssq[r], m, 64);
  float inv[4];
#pragma unroll
  for (int r = 0; r < 4; ++r) inv[r] = rsqrtf(ssq[r]);
#pragma unroll
  for (int c = 0; c < 5; ++c)
#pragma unroll
    for (int js = 0; js < 4; ++js) {
      int n = c * 64 + js * 16 + lc;
#pragma unroll
      for (int r = 0; r < 4; ++r) {
        int row = i0 + wave * 16 + g * 4 + r;
        fb[(size_t)row * D_PAD + n] = __float2bfloat16(h2a[c][js][r] * inv[r]);
      }
    }
}

// ---------- merged: symmetric dense pairwise (b<4096) + per-group sparse (b>=4096) ----------
__global__ __launch_bounds__(256, 2) void pg_kernel(
    const __hip_bfloat16* __restrict__ Fb, const int* __restrict__ labels,
    float* __restrict__ sEar, float* __restrict__ sPar, float* __restrict__ sAar)
{
  __shared__ __align__(16) short Bs[64 * D_PAD];
  __shared__ float colAcc[128];
  __shared__ int memb[256];
  __shared__ int cnt;
  const short* Fs = (const short*)Fb;
  int tid = threadIdx.x;
  int lane = tid & 63, wave = tid >> 6;
  int g = lane >> 4, lc = lane & 15, sw = lc & 7;
  int b = blockIdx.x;

  if (b < 4096) {
    // ---- dense symmetric pass: 128x128 tile (bi, bj), upper triangle only ----
    int bi = b >> 6, bj = b & 63;
    if (bj < bi) return;
    bool diag = (bi == bj);
    int i0 = bi * 128, j0 = bj * 128;
    if (tid < 128) colAcc[tid] = 0.f;

    short8v afr[2][10];
    for (int s = 0; s < 2; ++s) {
      const short* ap = Fs + (size_t)(i0 + s * 64 + wave * 16 + lc) * D_PAD + g * 8;
#pragma unroll
      for (int kk = 0; kk < 10; ++kk) afr[s][kk] = *(const short8v*)(ap + kk * 32);
    }
    float sE[2][4] = {};

    for (int jt = 0; jt < 2; ++jt) {
      int jb = j0 + jt * 64;
      __syncthreads();
      {
        const int4* src = (const int4*)Fs;
        int4* dst = (int4*)Bs;
#pragma unroll
        for (int t = 0; t < 10; ++t) {
          int e = tid + t * 256;
          int r = e / 40, q = e - r * 40;
          dst[r * 40 + (q ^ (r & 7))] = src[(size_t)(jb + r) * 40 + q];
        }
      }
      __syncthreads();
      for (int js = 0; js < 4; ++js) {
        float4v acc0 = {0.f, 0.f, 0.f, 0.f}, acc1 = {0.f, 0.f, 0.f, 0.f};
        const short* rowp = Bs + (js * 16 + lc) * D_PAD;
#pragma unroll
        for (int kk = 0; kk < 10; ++kk) {
          short8v bf = *(const short8v*)(rowp + (((g + 4 * kk) ^ sw) << 3));
          acc0 = __builtin_amdgcn_mfma_f32_16x16x32_bf16(afr[0][kk], bf, acc0, 0, 0, 0);
          acc1 = __builtin_amdgcn_mfma_f32_16x16x32_bf16(afr[1][kk], bf, acc1, 0, 0, 0);
        }
#pragma unroll
        for (int s = 0; s < 2; ++s) {
          float4v acc = s ? acc1 : acc0;
          bool dt = diag && (jt == s) && (js == wave);
          float cs = 0.f;
#pragma unroll
          for (int r = 0; r < 4; ++r) {
            float e = exp2f(fmaf(acc[r], LOG2E100, -LOG2E100));
            if (dt && lc == g * 4 + r) e = 0.0f;   // self-pair excluded
            sE[s][r] += e;
            cs += e;
          }
          if (!diag) {                 // column sums -> sE[j] (symmetry)
            cs += __shfl_xor(cs, 16, 64);
            cs += __shfl_xor(cs, 32, 64);
            if (g == 0) atomicAdd(&colAcc[jt * 64 + js * 16 + lc], cs);
          }
        }
      }
    }
    for (int m = 1; m < 16; m <<= 1)
#pragma unroll
      for (int s = 0; s < 2; ++s)
#pragma unroll
        for (int r = 0; r < 4; ++r) sE[s][r] += __shfl_xor(sE[s][r], m, 64);
    if (lc == 0)
      for (int s = 0; s < 2; ++s)
        for (int r = 0; r < 4; ++r)
          atomicAdd(&sEar[i0 + s * 64 + wave * 16 + g * 4 + r], sE[s][r]);
    if (!diag) {
      __syncthreads();
      if (tid < 128) atomicAdd(&sEar[j0 + tid], colAcc[tid]);
    }
  } else {
    // ---- sparse per-group pass: sP_i, sA_i over same-label pairs ----
    int grp = b - 4096 + 1;
    if (tid == 0) cnt = 0;
    __syncthreads();
    for (int i = tid; i < N_ROWS; i += 256)
      if (labels[i] == grp) { int p = atomicAdd(&cnt, 1); if (p < 256) memb[p] = i; }
    __syncthreads();
    int c = cnt > 256 ? 256 : cnt;
    int nt = (c + 63) >> 6;
    for (int it = 0; it < nt; ++it) {
      short8v afr[10];
      {
        int islot = it * 64 + wave * 16 + lc;
        int arow = memb[islot < c ? islot : 0];
        const short* ap = Fs + (size_t)arow * D_PAD + g * 8;
#pragma unroll
        for (int kk = 0; kk < 10; ++kk) afr[kk] = *(const short8v*)(ap + kk * 32);
      }
      int iglobr[4]; bool ivalid[4];
      for (int r = 0; r < 4; ++r) {
        int islot = it * 64 + wave * 16 + g * 4 + r;
        ivalid[r] = islot < c;
        iglobr[r] = memb[islot < c ? islot : 0];
      }
      float sp[4] = {}, sa[4] = {};
      for (int jt = 0; jt < nt; ++jt) {
        __syncthreads();
        {
          const int4* src = (const int4*)Fs;
          int4* dst = (int4*)Bs;
#pragma unroll
          for (int t = 0; t < 10; ++t) {
            int e = tid + t * 256;
            int r = e / 40, q = e - r * 40;
            int jslot = jt * 64 + r;
            int grow = memb[jslot < c ? jslot : 0];
            dst[r * 40 + (q ^ (r & 7))] = src[(size_t)grow * 40 + q];
          }
        }
        __syncthreads();
        for (int js = 0; js < 4; ++js) {
          float4v acc = {0.f, 0.f, 0.f, 0.f};
          const short* rowp = Bs + (js * 16 + lc) * D_PAD;
#pragma unroll
          for (int kk = 0; kk < 10; ++kk) {
            short8v bf = *(const short8v*)(rowp + (((g + 4 * kk) ^ sw) << 3));
            acc = __builtin_amdgcn_mfma_f32_16x16x32_bf16(afr[kk], bf, acc, 0, 0, 0);
          }
          int jslot = jt * 64 + js * 16 + lc;
          bool jv = jslot < c;
          int jglob = memb[jslot < c ? jslot : 0];
#pragma unroll
          for (int r = 0; r < 4; ++r) {
            float a = acc[r];
            float e = exp2f(fmaf(a, LOG2E100, -LOG2E100));
            bool ok = jv && ivalid[r] && (jglob != iglobr[r]);
            sp[r] += ok ? e : 0.f;
            sa[r] += ok ? a : 0.f;
          }
        }
      }
      for (int m = 1; m < 16; m <<= 1)
        for (int r = 0; r < 4; ++r) {
          sp[r] += __shfl_xor(sp[r], m, 64);
          sa[r] += __shfl_xor(sa[r], m, 64);
        }
      if (lc == 0)
        for (int r = 0; r < 4; ++r)
          if (ivalid[r]) { sPar[iglobr[r]] = sp[r]; sAar[iglobr[r]] = sa[r]; }
    }
  }
}

// ---------- final: per-row combine + loss reduce (single block) ----------
__global__ __launch_bounds__(1024) void final_kernel(
    const float* __restrict__ sEar, const float* __restrict__ sPar,
    const float* __restrict__ sAar, const int* __restrict__ counts,
    const int* __restrict__ labels, float* __restrict__ out)
{
  int tid = threadIdx.x;
  float sumM = 0.f, sumV = 0.f;
  for (int i = tid; i < N_ROWS; i += 1024) {
    int pc = counts[labels[i]] - 1;
    if (pc > 0) {
      float P = sPar[i], A = sAar[i];
      float Q = sEar[i] - P;
      float pcf = (float)pc, ncf = (float)(N_ROWS - 1 - pc);
      float Z = P / pcf + Q / ncf;
      sumM += 100.0f * A / pcf - 100.0f - logf(pcf) - logf(Z);
      sumV += 1.f;
    }
  }
  __shared__ float rm[1024], rv[1024];
  rm[tid] = sumM; rv[tid] = sumV;
  __syncthreads();
  for (int s = 512; s > 0; s >>= 1) {
    if (tid < s) { rm[tid] += rm[tid + s]; rv[tid] += rv[tid + s]; }
    __syncthreads();
  }
  if (tid == 0) out[0] = (rv[0] > 0.f) ? (-TEMP * rm[0] / rv[0]) : 0.f;
}

extern "C" void kernel_launch(void* const* d_in, const int* in_sizes, int n_in,
                              void* d_out, int out_size, void* d_ws, size_t ws_size,
                              hipStream_t stream)
{
  const float* x  = (const float*)d_in[0];
  const float* W1 = (const float*)d_in[1];
  const float* b1 = (const float*)d_in[2];
  const float* W2 = (const float*)d_in[3];
  const float* b2 = (const float*)d_in[4];
  const int* labels = (const int*)d_in[5];

  char* ws = (char*)d_ws;
  __hip_bfloat16* fb  = (__hip_bfloat16*)(ws);              // 5,242,880
  __hip_bfloat16* w1t = (__hip_bfloat16*)(ws + 5242880);    // 204,800
  __hip_bfloat16* w2t = (__hip_bfloat16*)(ws + 5447680);    // 204,800
  int*         counts = (int*)(ws + 5652480);               // 512
  float*        sEar  = (float*)(ws + 5652992);             // 32,768
  float*        sPar  = (float*)(ws + 5685760);             // 32,768
  float*        sAar  = (float*)(ws + 5718528);             // 32,768
  
  hipMemsetAsync(counts, 0, 512, stream);
  hipMemsetAsync(sEar, 0, N_ROWS * sizeof(float), stream);
  setup_kernel<<<82, 256, 0, stream>>>(W1, W2, labels, w1t, w2t, counts);
  mlp_fused_kernel<<<256, 128, 0, stream>>>(x, w1t, w2t, b1, b2, fb);
  pg_kernel<<<4096 + NG, 256, 0, stream>>>(fb, labels, sEar, sPar, sAar);
  final_kernel<<<1, 1024, 0, stream>>>(sEar, sPar, sAar, counts, labels, (float*)d_out);
}

// Round 6
// 193.680 us; speedup vs baseline: 1.2057x; 1.2057x over previous
//
#include <hip/hip_runtime.h>
#include <hip/hip_bf16.h>

// GroupContrast loss. Per-row reductions instead of the 8192x8192 logits:
//   dense pass:  sE_i = sum_{j != i} exp(100*acc_ij - 100)     (MFMA, full matrix)
//   group pass:  sP_i = sum_pos exp(..), sA_i = sum_pos acc    (sparse, ~1% of pairs,
//     same MFMA chain -> bitwise-identical acc, so Q = sE - sP is exact)
//   final: Z = sP/pc + (sE-sP)/nc;
//          mlpp = 100*sA/pc - 100 - log(pc) - log(Z); loss = -T*mean_valid.
// History:
//  - R3: __launch_bounds__(256,4) caps VGPR at 64 -> afr[][] spills to scratch
//    (328MB FETCH, 2x slower). (256,3) cap ~168 is safe for the ~108 needed.
//  - R5: symmetric upper-triangle pass halved MFMA busy-time but doubled wall
//    time (per-block overhead no longer amortized, dead blocks) -> reverted.
//  - MLP: W staged via LDS serialized on barriers; now B-frags read straight
//    from global (L2-hot, 400KB), 2 barriers total per block.

#define N_ROWS 8192
#define D_PAD 320
#define NG 100
#define TEMP 0.01f
#define NSPLIT 32
#define JCHUNK (N_ROWS / NSPLIT)   // 256
#define LOG2E100 144.2695041f      // 100 * log2(e)

typedef short short8v __attribute__((ext_vector_type(8)));
typedef float float4v __attribute__((ext_vector_type(4)));

__device__ __forceinline__ short f2bf(float f) {
  union { __hip_bfloat16 h; short s; } u;
  u.h = __float2bfloat16(f);
  return u.s;
}

// ---------- setup: W1/W2 -> bf16 Wt[320 n][320 k] (LDS-tiled transpose)
//            + per-block histogram partials (plain stores, no memset needed) ----------
__global__ __launch_bounds__(256) void setup_kernel(
    const float* __restrict__ W1, const float* __restrict__ W2,
    const int* __restrict__ labels,
    __hip_bfloat16* __restrict__ w1t, __hip_bfloat16* __restrict__ w2t,
    int* __restrict__ counts32)
{
  __shared__ float T[64][65];
  __shared__ int hc[NG + 1];
  int b = blockIdx.x, tid = threadIdx.x;
  if (b < 50) {                          // 25 tiles per matrix, 64x64
    int isW2 = b >= 25;
    int t5 = isW2 ? b - 25 : b;
    int k0 = (t5 / 5) * 64, n0 = (t5 % 5) * 64;
    const float* W = isW2 ? W2 : W1;
    __hip_bfloat16* dst = isW2 ? w2t : w1t;
#pragma unroll
    for (int t = 0; t < 16; ++t) {       // coalesced read along n
      int e = tid + t * 256;
      int r = e >> 6, c = e & 63;
      T[r][c] = (k0 + r < 300 && n0 + c < 300)
                  ? W[(size_t)(k0 + r) * 300 + (n0 + c)] : 0.0f;
    }
    __syncthreads();
#pragma unroll
    for (int t = 0; t < 16; ++t) {       // coalesced write along k
      int e = tid + t * 256;
      int nn = e >> 6, kk = e & 63;
      dst[(size_t)(n0 + nn) * D_PAD + (k0 + kk)] = __float2bfloat16(T[kk][nn]);
    }
  } else {                               // hist partials: block h owns 256 rows
    int h = b - 50;
    if (tid <= NG) hc[tid] = 0;
    __syncthreads();
    atomicAdd(&hc[labels[h * 256 + tid]], 1);
    __syncthreads();
    if (tid <= NG) counts32[h * (NG + 1) + tid] = hc[tid];   // plain store
  }
}

// ---------- fused MLP + rownorm: x -> fb (bf16, unit rows, padded to 320) ----------
// 256 blocks x 256 threads, 32 rows/block. Wave pair (strip=wave>>1) owns 16
// rows; p=wave&1 splits the 20 n-tiles. B-frags (W rows) read directly from
// global (L2-hot, no LDS staging). Only 2 barriers per block.
__global__ __launch_bounds__(256) void mlp_fused_kernel(
    const float* __restrict__ x, const __hip_bfloat16* __restrict__ w1t,
    const __hip_bfloat16* __restrict__ w2t, const float* __restrict__ b1,
    const float* __restrict__ b2, __hip_bfloat16* __restrict__ fb)
{
  __shared__ __align__(16) short H1[32 * D_PAD];   // 20480 B (swizzled)
  __shared__ float ssq_s[32];
  const short* W1s = (const short*)w1t;
  const short* W2s = (const short*)w2t;
  int tid = threadIdx.x;
  int lane = tid & 63, wave = tid >> 6;
  int strip = wave >> 1, p = wave & 1;
  int g = lane >> 4, lc = lane & 15, sw = lc & 7;
  int i0 = blockIdx.x * 32;

  if (tid < 32) ssq_s[tid] = 0.f;

  // ---- A-frags from x rows i0+strip*16+lc (fp32 -> bf16) ----
  short8v afr[10];
  {
    const float* xp = x + (size_t)(i0 + strip * 16 + lc) * 300;
#pragma unroll
    for (int kk = 0; kk < 10; ++kk) {
      int k0 = kk * 32 + g * 8;
      short8v v;
      if (k0 + 8 <= 300) {
        float4 a = *(const float4*)(xp + k0);
        float4 c = *(const float4*)(xp + k0 + 4);
        v[0] = f2bf(a.x); v[1] = f2bf(a.y); v[2] = f2bf(a.z); v[3] = f2bf(a.w);
        v[4] = f2bf(c.x); v[5] = f2bf(c.y); v[6] = f2bf(c.z); v[7] = f2bf(c.w);
      } else if (k0 < 300) {     // k0 == 296
        float4 a = *(const float4*)(xp + k0);
        v[0] = f2bf(a.x); v[1] = f2bf(a.y); v[2] = f2bf(a.z); v[3] = f2bf(a.w);
        v[4] = 0; v[5] = 0; v[6] = 0; v[7] = 0;
      } else {
        v = short8v{0, 0, 0, 0, 0, 0, 0, 0};
      }
      afr[kk] = v;
    }
  }

  // ---- GEMM1: h1 = relu(x @ W1 + b1) -> H1 (bf16, swizzled), B from global ----
  for (int nt = 0; nt < 10; ++nt) {
    int n = (p * 10 + nt) * 16 + lc;
    float4v acc = {0.f, 0.f, 0.f, 0.f};
    const short* wp = W1s + (size_t)n * D_PAD + g * 8;
#pragma unroll
    for (int kk = 0; kk < 10; ++kk) {
      short8v bf = *(const short8v*)(wp + kk * 32);
      acc = __builtin_amdgcn_mfma_f32_16x16x32_bf16(afr[kk], bf, acc, 0, 0, 0);
    }
    float bv = (n < 300) ? b1[n] : 0.0f;
    int q = n >> 3;
#pragma unroll
    for (int r = 0; r < 4; ++r) {
      int row = strip * 16 + g * 4 + r;
      H1[row * D_PAD + ((q ^ (row & 7)) << 3) + (n & 7)] =
          f2bf(fmaxf(acc[r] + bv, 0.0f));
    }
  }
  __syncthreads();   // H1 complete (also orders ssq_s zeroing)

  // ---- h1 A-frags from LDS ----
  short8v hfr[10];
  {
    const short* rp = H1 + (strip * 16 + lc) * D_PAD;
#pragma unroll
    for (int kk = 0; kk < 10; ++kk)
      hfr[kk] = *(const short8v*)(rp + (((g + 4 * kk) ^ sw) << 3));
  }

  // ---- GEMM2: h2 = h1 @ W2 + b2, kept in registers, B from global ----
  float4v h2a[10];
  for (int nt = 0; nt < 10; ++nt) {
    int n = (p * 10 + nt) * 16 + lc;
    float4v acc = {0.f, 0.f, 0.f, 0.f};
    const short* wp = W2s + (size_t)n * D_PAD + g * 8;
#pragma unroll
    for (int kk = 0; kk < 10; ++kk) {
      short8v bf = *(const short8v*)(wp + kk * 32);
      acc = __builtin_amdgcn_mfma_f32_16x16x32_bf16(hfr[kk], bf, acc, 0, 0, 0);
    }
    float bv = (n < 300) ? b2[n] : 0.0f;
#pragma unroll
    for (int r = 0; r < 4; ++r) acc[r] += bv;   // pad cols: W/b pads=0 -> h2=0
    h2a[nt] = acc;
  }

  // ---- row ssq: lc-shuffle reduce, combine wave pair via LDS atomics ----
  float ss[4] = {0.f, 0.f, 0.f, 0.f};
#pragma unroll
  for (int nt = 0; nt < 10; ++nt)
#pragma unroll
    for (int r = 0; r < 4; ++r) ss[r] = fmaf(h2a[nt][r], h2a[nt][r], ss[r]);
  for (int m = 1; m < 16; m <<= 1)
#pragma unroll
    for (int r = 0; r < 4; ++r) ss[r] += __shfl_xor(ss[r], m, 64);
  if (lc == 0)
#pragma unroll
    for (int r = 0; r < 4; ++r) atomicAdd(&ssq_s[strip * 16 + g * 4 + r], ss[r]);
  __syncthreads();
  float inv[4];
#pragma unroll
  for (int r = 0; r < 4; ++r) inv[r] = rsqrtf(ssq_s[strip * 16 + g * 4 + r]);
#pragma unroll
  for (int nt = 0; nt < 10; ++nt) {
    int n = (p * 10 + nt) * 16 + lc;
#pragma unroll
    for (int r = 0; r < 4; ++r) {
      int row = i0 + strip * 16 + g * 4 + r;
      fb[(size_t)row * D_PAD + n] = __float2bfloat16(h2a[nt][r] * inv[r]);
    }
  }
}

// ---------- merged: dense pairwise (b<2048) + per-group sparse (b>=2048) ----------
__global__ __launch_bounds__(256, 3) void pg_kernel(
    const __hip_bfloat16* __restrict__ Fb, const int* __restrict__ labels,
    float* __restrict__ partE, float* __restrict__ sPar, float* __restrict__ sAar)
{
  __shared__ __align__(16) short Bs[64 * D_PAD];
  __shared__ int memb[256];
  __shared__ int cnt;
  const short* Fs = (const short*)Fb;
  int tid = threadIdx.x;
  int lane = tid & 63, wave = tid >> 6;
  int g = lane >> 4, lc = lane & 15, sw = lc & 7;
  int b = blockIdx.x;

  if (b < 2048) {
    // ---- dense: 128 i-rows (2 strips) x one 256-col j-split ----
    int bi = b >> 5, split = b & 31;
    int i0 = bi * 128;
    int jstart = split * JCHUNK;

    short8v afr[2][10];
    for (int s = 0; s < 2; ++s) {
      const short* ap = Fs + (size_t)(i0 + s * 64 + wave * 16 + lc) * D_PAD + g * 8;
#pragma unroll
      for (int kk = 0; kk < 10; ++kk) afr[s][kk] = *(const short8v*)(ap + kk * 32);
    }
    float sE[2][4] = {};

    for (int jt = 0; jt < JCHUNK / 64; ++jt) {
      int jb = jstart + jt * 64;
      __syncthreads();
      {
        const int4* src = (const int4*)Fs;
        int4* dst = (int4*)Bs;
#pragma unroll
        for (int t = 0; t < 10; ++t) {
          int e = tid + t * 256;
          int r = e / 40, q = e - r * 40;
          dst[r * 40 + (q ^ (r & 7))] = src[(size_t)(jb + r) * 40 + q];
        }
      }
      __syncthreads();
      for (int js = 0; js < 4; ++js) {
        float4v acc0 = {0.f, 0.f, 0.f, 0.f}, acc1 = {0.f, 0.f, 0.f, 0.f};
        const short* rowp = Bs + (js * 16 + lc) * D_PAD;
#pragma unroll
        for (int kk = 0; kk < 10; ++kk) {
          short8v bf = *(const short8v*)(rowp + (((g + 4 * kk) ^ sw) << 3));
          acc0 = __builtin_amdgcn_mfma_f32_16x16x32_bf16(afr[0][kk], bf, acc0, 0, 0, 0);
          acc1 = __builtin_amdgcn_mfma_f32_16x16x32_bf16(afr[1][kk], bf, acc1, 0, 0, 0);
        }
#pragma unroll
        for (int s = 0; s < 2; ++s) {
          float4v acc = s ? acc1 : acc0;
          bool dt = (jb == i0 + s * 64) && (js == wave);
#pragma unroll
          for (int r = 0; r < 4; ++r) {
            float e = exp2f(fmaf(acc[r], LOG2E100, -LOG2E100));
            // diagonal excluded here (cannot be reconstructed later without
            // catastrophic cancellation against the ~1e-30-scale sums)
            if (dt && lc == g * 4 + r) e = 0.0f;
            sE[s][r] += e;
          }
        }
      }
    }
    for (int m = 1; m < 16; m <<= 1)
#pragma unroll
      for (int s = 0; s < 2; ++s)
#pragma unroll
        for (int r = 0; r < 4; ++r) sE[s][r] += __shfl_xor(sE[s][r], m, 64);
    if (lc == 0)
      for (int s = 0; s < 2; ++s)
        for (int r = 0; r < 4; ++r)
          partE[split * N_ROWS + i0 + s * 64 + wave * 16 + g * 4 + r] = sE[s][r];
  } else {
    // ---- sparse per-group pass: sP_i, sA_i over same-label pairs ----
    int grp = b - 2048 + 1;
    if (tid == 0) cnt = 0;
    __syncthreads();
    for (int i = tid; i < N_ROWS; i += 256)
      if (labels[i] == grp) { int pp = atomicAdd(&cnt, 1); if (pp < 256) memb[pp] = i; }
    __syncthreads();
    int c = cnt > 256 ? 256 : cnt;
    int nt = (c + 63) >> 6;
    for (int it = 0; it < nt; ++it) {
      short8v afr[10];
      {
        int islot = it * 64 + wave * 16 + lc;
        int arow = memb[islot < c ? islot : 0];
        const short* ap = Fs + (size_t)arow * D_PAD + g * 8;
#pragma unroll
        for (int kk = 0; kk < 10; ++kk) afr[kk] = *(const short8v*)(ap + kk * 32);
      }
      int iglobr[4]; bool ivalid[4];
      for (int r = 0; r < 4; ++r) {
        int islot = it * 64 + wave * 16 + g * 4 + r;
        ivalid[r] = islot < c;
        iglobr[r] = memb[islot < c ? islot : 0];
      }
      float sp[4] = {}, sa[4] = {};
      for (int jt = 0; jt < nt; ++jt) {
        __syncthreads();
        {
          const int4* src = (const int4*)Fs;
          int4* dst = (int4*)Bs;
#pragma unroll
          for (int t = 0; t < 10; ++t) {
            int e = tid + t * 256;
            int r = e / 40, q = e - r * 40;
            int jslot = jt * 64 + r;
            int grow = memb[jslot < c ? jslot : 0];
            dst[r * 40 + (q ^ (r & 7))] = src[(size_t)grow * 40 + q];
          }
        }
        __syncthreads();
        for (int js = 0; js < 4; ++js) {
          float4v acc = {0.f, 0.f, 0.f, 0.f};
          const short* rowp = Bs + (js * 16 + lc) * D_PAD;
#pragma unroll
          for (int kk = 0; kk < 10; ++kk) {
            short8v bf = *(const short8v*)(rowp + (((g + 4 * kk) ^ sw) << 3));
            acc = __builtin_amdgcn_mfma_f32_16x16x32_bf16(afr[kk], bf, acc, 0, 0, 0);
          }
          int jslot = jt * 64 + js * 16 + lc;
          bool jv = jslot < c;
          int jglob = memb[jslot < c ? jslot : 0];
#pragma unroll
          for (int r = 0; r < 4; ++r) {
            float a = acc[r];
            float e = exp2f(fmaf(a, LOG2E100, -LOG2E100));
            bool ok = jv && ivalid[r] && (jglob != iglobr[r]);
            sp[r] += ok ? e : 0.f;
            sa[r] += ok ? a : 0.f;
          }
        }
      }
      for (int m = 1; m < 16; m <<= 1)
        for (int r = 0; r < 4; ++r) {
          sp[r] += __shfl_xor(sp[r], m, 64);
          sa[r] += __shfl_xor(sa[r], m, 64);
        }
      if (lc == 0)
        for (int r = 0; r < 4; ++r)
          if (ivalid[r]) { sPar[iglobr[r]] = sp[r]; sAar[iglobr[r]] = sa[r]; }
    }
  }
}

// ---------- final: counts combine + per-row mlpp + loss reduce (1 block) ----------
__global__ __launch_bounds__(1024) void final_kernel(
    const float* __restrict__ partE, const float* __restrict__ sPar,
    const float* __restrict__ sAar, const int* __restrict__ counts32,
    const int* __restrict__ labels, float* __restrict__ out)
{
  __shared__ int cnt_s[NG + 1];
  __shared__ float rm[1024], rv[1024];
  int tid = threadIdx.x;
  if (tid <= NG) {
    int c = 0;
    for (int s = 0; s < 32; ++s) c += counts32[s * (NG + 1) + tid];
    cnt_s[tid] = c;
  }
  __syncthreads();
  float sumM = 0.f, sumV = 0.f;
  for (int i = tid; i < N_ROWS; i += 1024) {
    float sE = 0.f;
    for (int s = 0; s < NSPLIT; ++s) sE += partE[s * N_ROWS + i];
    int pc = cnt_s[labels[i]] - 1;
    if (pc > 0) {
      float P = sPar[i], A = sAar[i];
      float Q = sE - P;
      float pcf = (float)pc, ncf = (float)(N_ROWS - 1 - pc);
      float Z = P / pcf + Q / ncf;
      sumM += 100.0f * A / pcf - 100.0f - logf(pcf) - logf(Z);
      sumV += 1.f;
    }
  }
  rm[tid] = sumM; rv[tid] = sumV;
  __syncthreads();
  for (int s = 512; s > 0; s >>= 1) {
    if (tid < s) { rm[tid] += rm[tid + s]; rv[tid] += rv[tid + s]; }
    __syncthreads();
  }
  if (tid == 0) out[0] = (rv[0] > 0.f) ? (-TEMP * rm[0] / rv[0]) : 0.f;
}

extern "C" void kernel_launch(void* const* d_in, const int* in_sizes, int n_in,
                              void* d_out, int out_size, void* d_ws, size_t ws_size,
                              hipStream_t stream)
{
  const float* x  = (const float*)d_in[0];
  const float* W1 = (const float*)d_in[1];
  const float* b1 = (const float*)d_in[2];
  const float* W2 = (const float*)d_in[3];
  const float* b2 = (const float*)d_in[4];
  const int* labels = (const int*)d_in[5];

  char* ws = (char*)d_ws;
  __hip_bfloat16* fb   = (__hip_bfloat16*)(ws);             // 5,242,880
  __hip_bfloat16* w1t  = (__hip_bfloat16*)(ws + 5242880);   // 204,800
  __hip_bfloat16* w2t  = (__hip_bfloat16*)(ws + 5447680);   // 204,800
  int*         counts32 = (int*)(ws + 5652480);             // 12,928 (pad 13,056)
  float*        partE  = (float*)(ws + 5665536);            // 1,048,576
  float*        sPar   = (float*)(ws + 6714112);            // 32,768
  float*        sAar   = (float*)(ws + 6746880);            // 32,768

  setup_kernel<<<82, 256, 0, stream>>>(W1, W2, labels, w1t, w2t, counts32);
  mlp_fused_kernel<<<256, 256, 0, stream>>>(x, w1t, w2t, b1, b2, fb);
  pg_kernel<<<2048 + NG, 256, 0, stream>>>(fb, labels, partE, sPar, sAar);
  final_kernel<<<1, 1024, 0, stream>>>(partE, sPar, sAar, counts32, labels, (float*)d_out);
}